// Round 2
// baseline (580.976 us; speedup 1.0000x reference)
//
#include <hip/hip_runtime.h>
#include <hip/hip_bf16.h>

// Problem: N=32, T=2048, H=1024, D=384
//   h_proj = gru(N,T,H) @ W_h(H,H); energy = tanh(h_proj + c_proj + bias)
//   scores = energy . v ; weights = softmax_T(scores); context = sum_t w*gru
#define N_B 32
#define T_S 2048
#define H_D 1024
#define D_C 384
#define NT  (N_B * T_S)   // 65536

typedef __attribute__((ext_vector_type(8))) short bf16x8;
typedef __attribute__((ext_vector_type(4))) float f32x4;

__device__ __forceinline__ ushort f2bf(float f) {
    union { float f; unsigned u; } x; x.f = f;
    unsigned u = x.u;
    unsigned r = (u + 0x7FFFu + ((u >> 16) & 1u)) >> 16;  // RNE
    return (ushort)r;
}

__device__ __forceinline__ float bf2f(ushort u) {
    union { unsigned u; float f; } x; x.u = ((unsigned)u) << 16;
    return x.f;
}

__device__ __forceinline__ float fast_tanh(float x) {
    float e = __expf(2.0f * x);
    return 1.0f - 2.0f / (e + 1.0f);
}

// async global->LDS, 16B per lane; LDS dest = wave-uniform base + lane*16
__device__ __forceinline__ void gl2lds16(const void* g, void* l) {
    __builtin_amdgcn_global_load_lds(
        (const __attribute__((address_space(1))) void*)g,
        (__attribute__((address_space(3))) void*)l, 16, 0, 0);
}

// ---------------- gru fp32 -> bf16, fully lane-contiguous (16B load / 8B store)
__global__ __launch_bounds__(256) void convert_kernel(
    const float* __restrict__ g, ushort* __restrict__ gb)
{
    const size_t base = ((size_t)blockIdx.x * 256 + threadIdx.x) * 4;
    float4 v = *(const float4*)(g + base);
    ushort4 o;
    o.x = f2bf(v.x); o.y = f2bf(v.y); o.z = f2bf(v.z); o.w = f2bf(v.w);
    *(ushort4*)(gb + base) = o;
}

// ---------------- W_h (H,H) fp32 -> Wt (H,H) bf16 transposed: Wt[k][h] = W_h[h][k]
__global__ __launch_bounds__(256) void transpose_kernel(
    const float* __restrict__ W, ushort* __restrict__ Wt)
{
    __shared__ ushort tile[64 * 66];
    const int bx = blockIdx.x & 15;
    const int by = blockIdx.x >> 4;
    const int t = threadIdx.x;
    #pragma unroll
    for (int i = 0; i < 16; ++i) {
        int idx = t + i * 256;
        int r = idx >> 6, c = idx & 63;
        tile[r * 66 + c] = f2bf(W[(size_t)(by * 64 + r) * H_D + bx * 64 + c]);
    }
    __syncthreads();
    #pragma unroll
    for (int i = 0; i < 16; ++i) {
        int idx = t + i * 256;
        int r = idx >> 6, c = idx & 63;
        Wt[(size_t)(bx * 64 + r) * H_D + by * 64 + c] = tile[c * 66 + r];
    }
}

// ---------------- c_proj[n,k] += sum_{d in slice} cond[n,d]*W_c[d,k] (+bias)
__global__ __launch_bounds__(256) void cproj_kernel(
    const float* __restrict__ cond, const float* __restrict__ Wc,
    const float* __restrict__ bias, float* __restrict__ cproj)
{
    const int idx = blockIdx.x * 256 + threadIdx.x;  // 32768
    const int n = idx >> 10, k = idx & 1023;
    const int d0 = blockIdx.y * 96;
    float a0 = (blockIdx.y == 0) ? bias[k] : 0.f;
    float a1 = 0.f, a2 = 0.f, a3 = 0.f;
    const float* cp = cond + n * D_C;
    for (int d = d0; d < d0 + 96; d += 4) {
        a0 = fmaf(cp[d + 0], Wc[(size_t)(d + 0) * H_D + k], a0);
        a1 = fmaf(cp[d + 1], Wc[(size_t)(d + 1) * H_D + k], a1);
        a2 = fmaf(cp[d + 2], Wc[(size_t)(d + 2) * H_D + k], a2);
        a3 = fmaf(cp[d + 3], Wc[(size_t)(d + 3) * H_D + k], a3);
    }
    atomicAdd(&cproj[idx], (a0 + a1) + (a2 + a3));
}

// ---------------- GEMM + tanh + dot-v -> per-nb partial scores
// 256x256 tile, BK=32, quad-buffered LDS, 3-tiles-ahead counted-vmcnt pipeline.
// 8 waves (2M x 4N), per-wave output 128x64. One raw s_barrier per K-tile;
// vmcnt never drains to 0 in the main loop (T3+T4), setprio around MFMA (T5).
// lgkmcnt(0) folded into the pre-barrier wait: guarantees every wave's
// ds_reads of the buffer about to be overwritten are drained before any
// wave crosses the barrier (closes the rule-#18 MFMA-sink race).
#define BKq 32
#define TILE_U (256 * BKq)   // 8192 ushorts = 16 KiB per buf per tensor

__global__ __launch_bounds__(512, 2) void gemm4_kernel(
    const ushort* __restrict__ Ab, const ushort* __restrict__ Wt,
    const float* __restrict__ cproj, const float* __restrict__ v,
    float* __restrict__ spart)
{
    __shared__ __align__(16) ushort As[4][TILE_U];   // 64 KiB
    __shared__ __align__(16) ushort Bs[4][TILE_U];   // 64 KiB
    __shared__ float red[2][4][128];                 // 4 KiB

    // XCD-aware swizzle (1024 % 8 == 0 -> simple bijective form)
    const int bid = blockIdx.x;
    const int wg  = (bid & 7) * 128 + (bid >> 3);
    const int mb  = wg & 255;         // 256 M-blocks of 256 rows
    const int nb  = wg >> 8;          // 4 N-blocks of 256 cols
    const int m0  = mb * 256;
    const int n0  = nb * 256;
    const int nbatch = mb >> 3;       // 2048 rows per batch / 256 per block

    const int t = threadIdx.x;
    const int lane = t & 63;
    const int w = t >> 6;             // 0..7
    const int wm = w >> 2, wn = w & 3;
    const int ln = lane & 15, q = lane >> 4;
    // read-side chunk swizzle: chunk' = q ^ (row&3) ^ ((row>>2)&3); row bits == ln bits
    const int csw = q ^ (ln & 3) ^ ((ln >> 2) & 3);

    // staging: linear LDS dest (wave-uniform base + lane*16), inverse-swizzled global src
    const int slab = w * 2;           // 16-row slabs; wave covers slab, slab+1
    const int Rl = lane >> 2;         // row within slab
    const int gsw = ((lane & 3) ^ ((lane >> 2) & 3) ^ (lane >> 4)) * 8;  // src col (elems)

    const ushort* aS0 = Ab + (size_t)(m0 + slab * 16 + Rl) * H_D + gsw;
    const ushort* aS1 = aS0 + (size_t)16 * H_D;
    const ushort* bS0 = Wt + (size_t)(n0 + slab * 16 + Rl) * H_D + gsw;
    const ushort* bS1 = bS0 + (size_t)16 * H_D;
    ushort* aD = (ushort*)As + slab * 512;
    ushort* bD = (ushort*)Bs + slab * 512;

    const ushort* aR = (const ushort*)As + (wm * 128 + ln) * BKq + csw * 8;
    const ushort* bR = (const ushort*)Bs + (wn * 64  + ln) * BKq + csw * 8;

    f32x4 acc[8][4];
    #pragma unroll
    for (int i = 0; i < 8; ++i)
        #pragma unroll
        for (int j = 0; j < 4; ++j)
            acc[i][j] = (f32x4){0.f, 0.f, 0.f, 0.f};

#define ISSUE_A(kt, WB) do { const int _o = (kt) * BKq; \
    gl2lds16(aS0 + _o, aD + (WB) * TILE_U); \
    gl2lds16(aS1 + _o, aD + (WB) * TILE_U + 512); } while (0)
#define ISSUE_B(kt, WB) do { const int _o = (kt) * BKq; \
    gl2lds16(bS0 + _o, bD + (WB) * TILE_U); \
    gl2lds16(bS1 + _o, bD + (WB) * TILE_U + 512); } while (0)

#define MF(i,j,A,B) acc[i][j] = __builtin_amdgcn_mfma_f32_16x16x32_bf16(A, B, acc[i][j], 0, 0, 0)

#define TILE(kt, RB, WB, WAIT, DOISS) do { \
    asm volatile("s_waitcnt " WAIT ::: "memory"); \
    __builtin_amdgcn_s_barrier(); \
    __builtin_amdgcn_sched_barrier(0); \
    const ushort* _ar = aR + (RB) * TILE_U; \
    const ushort* _br = bR + (RB) * TILE_U; \
    bf16x8 _b0 = *(const bf16x8*)(_br); \
    bf16x8 _b1 = *(const bf16x8*)(_br + 512); \
    bf16x8 _b2 = *(const bf16x8*)(_br + 1024); \
    bf16x8 _b3 = *(const bf16x8*)(_br + 1536); \
    bf16x8 _a0 = *(const bf16x8*)(_ar); \
    bf16x8 _a1 = *(const bf16x8*)(_ar + 512); \
    bf16x8 _a2 = *(const bf16x8*)(_ar + 1024); \
    bf16x8 _a3 = *(const bf16x8*)(_ar + 1536); \
    if (DOISS) ISSUE_A((kt) + 3, WB); \
    __builtin_amdgcn_s_setprio(1); \
    MF(0,0,_a0,_b0); MF(0,1,_a0,_b1); MF(0,2,_a0,_b2); MF(0,3,_a0,_b3); \
    MF(1,0,_a1,_b0); MF(1,1,_a1,_b1); MF(1,2,_a1,_b2); MF(1,3,_a1,_b3); \
    MF(2,0,_a2,_b0); MF(2,1,_a2,_b1); MF(2,2,_a2,_b2); MF(2,3,_a2,_b3); \
    MF(3,0,_a3,_b0); MF(3,1,_a3,_b1); MF(3,2,_a3,_b2); MF(3,3,_a3,_b3); \
    __builtin_amdgcn_s_setprio(0); \
    bf16x8 _a4 = *(const bf16x8*)(_ar + 2048); \
    bf16x8 _a5 = *(const bf16x8*)(_ar + 2560); \
    bf16x8 _a6 = *(const bf16x8*)(_ar + 3072); \
    bf16x8 _a7 = *(const bf16x8*)(_ar + 3584); \
    if (DOISS) ISSUE_B((kt) + 3, WB); \
    __builtin_amdgcn_s_setprio(1); \
    MF(4,0,_a4,_b0); MF(4,1,_a4,_b1); MF(4,2,_a4,_b2); MF(4,3,_a4,_b3); \
    MF(5,0,_a5,_b0); MF(5,1,_a5,_b1); MF(5,2,_a5,_b2); MF(5,3,_a5,_b3); \
    MF(6,0,_a6,_b0); MF(6,1,_a6,_b1); MF(6,2,_a6,_b2); MF(6,3,_a6,_b3); \
    MF(7,0,_a7,_b0); MF(7,1,_a7,_b1); MF(7,2,_a7,_b2); MF(7,3,_a7,_b3); \
    __builtin_amdgcn_s_setprio(0); \
} while (0)

    // prologue: 3 tiles in flight (12 loads/thread)
    ISSUE_A(0, 0); ISSUE_B(0, 0);
    ISSUE_A(1, 1); ISSUE_B(1, 1);
    ISSUE_A(2, 2); ISSUE_B(2, 2);

    #pragma unroll 1
    for (int kt = 0; kt < 28; kt += 4) {
        TILE(kt + 0, 0, 3, "vmcnt(8) lgkmcnt(0)", true);
        TILE(kt + 1, 1, 0, "vmcnt(8) lgkmcnt(0)", true);
        TILE(kt + 2, 2, 1, "vmcnt(8) lgkmcnt(0)", true);
        TILE(kt + 3, 3, 2, "vmcnt(8) lgkmcnt(0)", true);
    }
    TILE(28, 0, 3, "vmcnt(8) lgkmcnt(0)", true);    // issues tile 31
    TILE(29, 1, 0, "vmcnt(8) lgkmcnt(0)", false);
    TILE(30, 2, 0, "vmcnt(4) lgkmcnt(0)", false);
    TILE(31, 3, 0, "vmcnt(0) lgkmcnt(0)", false);

    // epilogue: tanh + dot-v + per-row partial score over this block's 256 cols
    float cpv[4], vv[4];
    {
        const float* cpn = cproj + (size_t)nbatch * H_D;
        #pragma unroll
        for (int j = 0; j < 4; ++j) {
            int col = n0 + wn * 64 + j * 16 + ln;
            cpv[j] = cpn[col];
            vv[j]  = v[col];
        }
    }
    #pragma unroll
    for (int i = 0; i < 8; ++i) {
        float s0 = 0.f, s1 = 0.f, s2 = 0.f, s3 = 0.f;
        #pragma unroll
        for (int j = 0; j < 4; ++j) {
            s0 += fast_tanh(acc[i][j][0] + cpv[j]) * vv[j];
            s1 += fast_tanh(acc[i][j][1] + cpv[j]) * vv[j];
            s2 += fast_tanh(acc[i][j][2] + cpv[j]) * vv[j];
            s3 += fast_tanh(acc[i][j][3] + cpv[j]) * vv[j];
        }
        #pragma unroll
        for (int off = 1; off < 16; off <<= 1) {
            s0 += __shfl_xor(s0, off);
            s1 += __shfl_xor(s1, off);
            s2 += __shfl_xor(s2, off);
            s3 += __shfl_xor(s3, off);
        }
        if (ln == 0) {
            red[wm][wn][i * 16 + q * 4 + 0] = s0;
            red[wm][wn][i * 16 + q * 4 + 1] = s1;
            red[wm][wn][i * 16 + q * 4 + 2] = s2;
            red[wm][wn][i * 16 + q * 4 + 3] = s3;
        }
    }
    __syncthreads();
    if (t < 256) {
        const int wm2 = t >> 7, row = t & 127;
        float val = red[wm2][0][row] + red[wm2][1][row]
                  + red[wm2][2][row] + red[wm2][3][row];
        spart[(size_t)nb * NT + m0 + wm2 * 128 + row] = val;
    }
}

// ---------------- softmax over T per n, summing 4 nb-partials; 1024 threads
__global__ __launch_bounds__(1024) void softmax8_kernel(
    const float* __restrict__ spart, float* __restrict__ weights)
{
    const int n = blockIdx.x;
    const int t = threadIdx.x;   // 0..1023
    __shared__ float red[1024];
    float s0 = 0.f, s1 = 0.f;
    #pragma unroll
    for (int kb = 0; kb < 4; ++kb) {
        s0 += spart[(size_t)kb * NT + n * T_S + t];
        s1 += spart[(size_t)kb * NT + n * T_S + 1024 + t];
    }
    red[t] = fmaxf(s0, s1); __syncthreads();
    for (int s = 512; s > 0; s >>= 1) {
        if (t < s) red[t] = fmaxf(red[t], red[t + s]);
        __syncthreads();
    }
    const float mx = red[0];
    __syncthreads();
    float e0 = __expf(s0 - mx), e1 = __expf(s1 - mx);
    red[t] = e0 + e1; __syncthreads();
    for (int s = 512; s > 0; s >>= 1) {
        if (t < s) red[t] += red[t + s];
        __syncthreads();
    }
    const float inv = 1.0f / red[0];
    weights[n * T_S + t] = e0 * inv;
    weights[n * T_S + 1024 + t] = e1 * inv;
}

// ---------------- context partials: cpart[tb][n][h] = sum_{t in slice} w*gru
__global__ __launch_bounds__(256) void context3_kernel(
    const ushort* __restrict__ Ab, const float* __restrict__ weights,
    float* __restrict__ cpart)
{
    const int tb = blockIdx.x;   // 0..15, 128 t each
    const int n  = blockIdx.y;   // 0..31
    const int t  = threadIdx.x;  // h-chunk: 4 h (8 B)
    float a0 = 0.f, a1 = 0.f, a2 = 0.f, a3 = 0.f;
    const float* wp = weights + n * T_S + tb * 128;
    const ushort* gp = Ab + (size_t)(n * T_S + tb * 128) * H_D + t * 4;
    #pragma unroll 8
    for (int tt = 0; tt < 128; ++tt) {
        float w = wp[tt];
        ushort4 gv = *(const ushort4*)(gp + (size_t)tt * H_D);
        a0 = fmaf(w, bf2f(gv.x), a0);
        a1 = fmaf(w, bf2f(gv.y), a1);
        a2 = fmaf(w, bf2f(gv.z), a2);
        a3 = fmaf(w, bf2f(gv.w), a3);
    }
    *(float4*)(cpart + ((size_t)tb * N_B + n) * H_D + t * 4) =
        make_float4(a0, a1, a2, a3);
}

// ---------------- out[n][h] = sum_tb cpart[tb][n][h]
__global__ __launch_bounds__(256) void reduce_kernel(
    const float* __restrict__ cpart, float* __restrict__ out)
{
    const int idx = blockIdx.x * 256 + threadIdx.x;  // 32768
    float s = 0.f;
    #pragma unroll
    for (int tb = 0; tb < 16; ++tb)
        s += cpart[(size_t)tb * (N_B * H_D) + idx];
    out[idx] = s;
}

extern "C" void kernel_launch(void* const* d_in, const int* in_sizes, int n_in,
                              void* d_out, int out_size, void* d_ws, size_t ws_size,
                              hipStream_t stream)
{
    const float* gru  = (const float*)d_in[0];
    const float* cond = (const float*)d_in[1];
    const float* W_h  = (const float*)d_in[2];
    const float* W_c  = (const float*)d_in[3];
    const float* bias = (const float*)d_in[4];
    const float* v    = (const float*)d_in[5];
    float* out = (float*)d_out;

    char* ws = (char*)d_ws;
    const size_t szAb    = (size_t)NT * H_D * 2;        // 128 MiB
    const size_t szWt    = (size_t)H_D * H_D * 2;       // 2 MiB
    const size_t szCproj = (size_t)N_B * H_D * 4;       // 128 KiB
    const size_t szSpart = (size_t)8 * NT * 4;          // 2 MiB (4 used)

    ushort* Ab    = (ushort*)ws;
    ushort* Wt    = (ushort*)(ws + szAb);
    float* cproj  = (float*)(ws + szAb + szWt);
    float* spart  = (float*)(ws + szAb + szWt + szCproj);
    float* cpart  = spart;   // reuse: spart dead after softmax; same 2 MiB
    float* wts    = (float*)(ws + szAb + szWt + szCproj + szSpart);

    hipMemsetAsync(cproj, 0, szCproj, stream);
    convert_kernel<<<65536, 256, 0, stream>>>(gru, Ab);
    transpose_kernel<<<256, 256, 0, stream>>>(W_h, Wt);
    cproj_kernel<<<dim3(128, 4), 256, 0, stream>>>(cond, W_c, bias, cproj);
    gemm4_kernel<<<1024, 512, 0, stream>>>(Ab, Wt, cproj, v, spart);
    softmax8_kernel<<<N_B, 1024, 0, stream>>>(spart, wts);
    context3_kernel<<<dim3(16, N_B), 256, 0, stream>>>(Ab, wts, cpart);
    reduce_kernel<<<128, 256, 0, stream>>>(cpart, out);
}

// Round 3
// 576.496 us; speedup vs baseline: 1.0078x; 1.0078x over previous
//
#include <hip/hip_runtime.h>
#include <hip/hip_bf16.h>

// Problem: N=32, T=2048, H=1024, D=384
//   h_proj = gru(N,T,H) @ W_h(H,H); energy = tanh(h_proj + c_proj + bias)
//   scores = energy . v ; weights = softmax_T(scores); context = sum_t w*gru
#define N_B 32
#define T_S 2048
#define H_D 1024
#define D_C 384
#define NT  (N_B * T_S)   // 65536

typedef __attribute__((ext_vector_type(8))) short bf16x8;
typedef __attribute__((ext_vector_type(4))) float f32x4;

__device__ __forceinline__ ushort f2bf(float f) {
    union { float f; unsigned u; } x; x.f = f;
    unsigned u = x.u;
    unsigned r = (u + 0x7FFFu + ((u >> 16) & 1u)) >> 16;  // RNE
    return (ushort)r;
}

__device__ __forceinline__ float bf2f(ushort u) {
    union { unsigned u; float f; } x; x.u = ((unsigned)u) << 16;
    return x.f;
}

__device__ __forceinline__ float fast_tanh(float x) {
    float e = __expf(2.0f * x);
    return 1.0f - 2.0f / (e + 1.0f);
}

// async global->LDS, 16B per lane; LDS dest = wave-uniform base + lane*16
__device__ __forceinline__ void gl2lds16(const void* g, void* l) {
    __builtin_amdgcn_global_load_lds(
        (const __attribute__((address_space(1))) void*)g,
        (__attribute__((address_space(3))) void*)l, 16, 0, 0);
}

// ---------------- gru fp32 -> bf16, fully lane-contiguous (16B load / 8B store)
__global__ __launch_bounds__(256) void convert_kernel(
    const float* __restrict__ g, ushort* __restrict__ gb)
{
    const size_t base = ((size_t)blockIdx.x * 256 + threadIdx.x) * 4;
    float4 v = *(const float4*)(g + base);
    ushort4 o;
    o.x = f2bf(v.x); o.y = f2bf(v.y); o.z = f2bf(v.z); o.w = f2bf(v.w);
    *(ushort4*)(gb + base) = o;
}

// ---------------- W_h (H,H) fp32 -> Wt (H,H) bf16 transposed: Wt[k][h] = W_h[h][k]
__global__ __launch_bounds__(256) void transpose_kernel(
    const float* __restrict__ W, ushort* __restrict__ Wt)
{
    __shared__ ushort tile[64 * 66];
    const int bx = blockIdx.x & 15;
    const int by = blockIdx.x >> 4;
    const int t = threadIdx.x;
    #pragma unroll
    for (int i = 0; i < 16; ++i) {
        int idx = t + i * 256;
        int r = idx >> 6, c = idx & 63;
        tile[r * 66 + c] = f2bf(W[(size_t)(by * 64 + r) * H_D + bx * 64 + c]);
    }
    __syncthreads();
    #pragma unroll
    for (int i = 0; i < 16; ++i) {
        int idx = t + i * 256;
        int r = idx >> 6, c = idx & 63;
        Wt[(size_t)(bx * 64 + r) * H_D + by * 64 + c] = tile[c * 66 + r];
    }
}

// ---------------- c_proj[n,k] += sum_{d in slice} cond[n,d]*W_c[d,k] (+bias)
__global__ __launch_bounds__(256) void cproj_kernel(
    const float* __restrict__ cond, const float* __restrict__ Wc,
    const float* __restrict__ bias, float* __restrict__ cproj)
{
    const int idx = blockIdx.x * 256 + threadIdx.x;  // 32768
    const int n = idx >> 10, k = idx & 1023;
    const int d0 = blockIdx.y * 96;
    float a0 = (blockIdx.y == 0) ? bias[k] : 0.f;
    float a1 = 0.f, a2 = 0.f, a3 = 0.f;
    const float* cp = cond + n * D_C;
    for (int d = d0; d < d0 + 96; d += 4) {
        a0 = fmaf(cp[d + 0], Wc[(size_t)(d + 0) * H_D + k], a0);
        a1 = fmaf(cp[d + 1], Wc[(size_t)(d + 1) * H_D + k], a1);
        a2 = fmaf(cp[d + 2], Wc[(size_t)(d + 2) * H_D + k], a2);
        a3 = fmaf(cp[d + 3], Wc[(size_t)(d + 3) * H_D + k], a3);
    }
    atomicAdd(&cproj[idx], (a0 + a1) + (a2 + a3));
}

// ---------------- GEMM + tanh + dot-v -> per-nb partial scores
// 256x256 tile, BK=32, quad-buffered LDS, 3-tiles-ahead counted-vmcnt pipeline.
// 8 waves (2M x 4N), per-wave output 128x64. One raw s_barrier per K-tile;
// vmcnt never drains to 0 in the main loop (T3+T4), setprio around MFMA (T5).
// lgkmcnt(0) folded into the pre-barrier wait (closes the rule-#18 race).
//
// R3 fixes vs R2 (counter-driven):
//  * LDS swizzle: f(r) = (r>>1)&3 (was (r&3)^((r>>2)&3)).  For 64B rows +
//    b128 reads, bank phase = 4*(ln&1) + chunk mod 8; f(r)=(r>>1)&3 makes
//    each 16-lane quarter hit all 8 phases exactly 2x (2-way = free, m136).
//    R2's pattern folded ln and ln+8 onto the same phase -> 4-way, 1.26e7
//    conflict counts.
//  * Block mapping: mb = wg>>2, nb = wg&3 (was mb = wg&255, nb = wg>>8).
//    Each XCD's 32 concurrent blocks now share 8 A-panels (4 MiB ~ L2) with
//    all 4 nb co-resident -> A filled ~once (R2: each XCD streamed 64 MiB
//    of A alone -> FETCH 270 MB vs gemm3's 82 MB).
#define BKq 32
#define TILE_U (256 * BKq)   // 8192 ushorts = 16 KiB per buf per tensor

__global__ __launch_bounds__(512, 2) void gemm4_kernel(
    const ushort* __restrict__ Ab, const ushort* __restrict__ Wt,
    const float* __restrict__ cproj, const float* __restrict__ v,
    float* __restrict__ spart)
{
    __shared__ __align__(16) ushort As[4][TILE_U];   // 64 KiB
    __shared__ __align__(16) ushort Bs[4][TILE_U];   // 64 KiB
    __shared__ float red[2][4][128];                 // 4 KiB

    // XCD-aware swizzle (1024 % 8 == 0 -> simple bijective form)
    const int bid = blockIdx.x;
    const int wg  = (bid & 7) * 128 + (bid >> 3);
    const int mb  = wg >> 2;          // 256 M-blocks of 256 rows
    const int nb  = wg & 3;           // 4 N-blocks of 256 cols
    const int m0  = mb * 256;
    const int n0  = nb * 256;
    const int nbatch = mb >> 3;       // 2048 rows per batch / 256 per block

    const int t = threadIdx.x;
    const int lane = t & 63;
    const int w = t >> 6;             // 0..7
    const int wm = w >> 2, wn = w & 3;
    const int ln = lane & 15, q = lane >> 4;
    // read-side chunk swizzle: chunk' = q ^ ((row>>1)&3); row bits come from ln
    const int csw = q ^ ((ln >> 1) & 3);

    // staging: linear LDS dest (wave-uniform base + lane*16), inverse-swizzled global src
    const int slab = w * 2;           // 16-row slabs; wave covers slab, slab+1
    const int Rl = lane >> 2;         // row within slab
    const int gsw = ((lane & 3) ^ ((lane >> 3) & 3)) * 8;  // src chunk (elems)

    const ushort* aS0 = Ab + (size_t)(m0 + slab * 16 + Rl) * H_D + gsw;
    const ushort* aS1 = aS0 + (size_t)16 * H_D;
    const ushort* bS0 = Wt + (size_t)(n0 + slab * 16 + Rl) * H_D + gsw;
    const ushort* bS1 = bS0 + (size_t)16 * H_D;
    ushort* aD = (ushort*)As + slab * 512;
    ushort* bD = (ushort*)Bs + slab * 512;

    const ushort* aR = (const ushort*)As + (wm * 128 + ln) * BKq + csw * 8;
    const ushort* bR = (const ushort*)Bs + (wn * 64  + ln) * BKq + csw * 8;

    f32x4 acc[8][4];
    #pragma unroll
    for (int i = 0; i < 8; ++i)
        #pragma unroll
        for (int j = 0; j < 4; ++j)
            acc[i][j] = (f32x4){0.f, 0.f, 0.f, 0.f};

#define ISSUE_A(kt, WB) do { const int _o = (kt) * BKq; \
    gl2lds16(aS0 + _o, aD + (WB) * TILE_U); \
    gl2lds16(aS1 + _o, aD + (WB) * TILE_U + 512); } while (0)
#define ISSUE_B(kt, WB) do { const int _o = (kt) * BKq; \
    gl2lds16(bS0 + _o, bD + (WB) * TILE_U); \
    gl2lds16(bS1 + _o, bD + (WB) * TILE_U + 512); } while (0)

#define MF(i,j,A,B) acc[i][j] = __builtin_amdgcn_mfma_f32_16x16x32_bf16(A, B, acc[i][j], 0, 0, 0)

#define TILE(kt, RB, WB, WAIT, DOISS) do { \
    asm volatile("s_waitcnt " WAIT ::: "memory"); \
    __builtin_amdgcn_s_barrier(); \
    __builtin_amdgcn_sched_barrier(0); \
    const ushort* _ar = aR + (RB) * TILE_U; \
    const ushort* _br = bR + (RB) * TILE_U; \
    bf16x8 _b0 = *(const bf16x8*)(_br); \
    bf16x8 _b1 = *(const bf16x8*)(_br + 512); \
    bf16x8 _b2 = *(const bf16x8*)(_br + 1024); \
    bf16x8 _b3 = *(const bf16x8*)(_br + 1536); \
    bf16x8 _a0 = *(const bf16x8*)(_ar); \
    bf16x8 _a1 = *(const bf16x8*)(_ar + 512); \
    bf16x8 _a2 = *(const bf16x8*)(_ar + 1024); \
    bf16x8 _a3 = *(const bf16x8*)(_ar + 1536); \
    if (DOISS) ISSUE_A((kt) + 3, WB); \
    __builtin_amdgcn_s_setprio(1); \
    MF(0,0,_a0,_b0); MF(0,1,_a0,_b1); MF(0,2,_a0,_b2); MF(0,3,_a0,_b3); \
    MF(1,0,_a1,_b0); MF(1,1,_a1,_b1); MF(1,2,_a1,_b2); MF(1,3,_a1,_b3); \
    MF(2,0,_a2,_b0); MF(2,1,_a2,_b1); MF(2,2,_a2,_b2); MF(2,3,_a2,_b3); \
    MF(3,0,_a3,_b0); MF(3,1,_a3,_b1); MF(3,2,_a3,_b2); MF(3,3,_a3,_b3); \
    __builtin_amdgcn_s_setprio(0); \
    bf16x8 _a4 = *(const bf16x8*)(_ar + 2048); \
    bf16x8 _a5 = *(const bf16x8*)(_ar + 2560); \
    bf16x8 _a6 = *(const bf16x8*)(_ar + 3072); \
    bf16x8 _a7 = *(const bf16x8*)(_ar + 3584); \
    if (DOISS) ISSUE_B((kt) + 3, WB); \
    __builtin_amdgcn_s_setprio(1); \
    MF(4,0,_a4,_b0); MF(4,1,_a4,_b1); MF(4,2,_a4,_b2); MF(4,3,_a4,_b3); \
    MF(5,0,_a5,_b0); MF(5,1,_a5,_b1); MF(5,2,_a5,_b2); MF(5,3,_a5,_b3); \
    MF(6,0,_a6,_b0); MF(6,1,_a6,_b1); MF(6,2,_a6,_b2); MF(6,3,_a6,_b3); \
    MF(7,0,_a7,_b0); MF(7,1,_a7,_b1); MF(7,2,_a7,_b2); MF(7,3,_a7,_b3); \
    __builtin_amdgcn_s_setprio(0); \
} while (0)

    // prologue: 3 tiles in flight (12 loads/thread)
    ISSUE_A(0, 0); ISSUE_B(0, 0);
    ISSUE_A(1, 1); ISSUE_B(1, 1);
    ISSUE_A(2, 2); ISSUE_B(2, 2);

    #pragma unroll 1
    for (int kt = 0; kt < 28; kt += 4) {
        TILE(kt + 0, 0, 3, "vmcnt(8) lgkmcnt(0)", true);
        TILE(kt + 1, 1, 0, "vmcnt(8) lgkmcnt(0)", true);
        TILE(kt + 2, 2, 1, "vmcnt(8) lgkmcnt(0)", true);
        TILE(kt + 3, 3, 2, "vmcnt(8) lgkmcnt(0)", true);
    }
    TILE(28, 0, 3, "vmcnt(8) lgkmcnt(0)", true);    // issues tile 31
    TILE(29, 1, 0, "vmcnt(8) lgkmcnt(0)", false);
    TILE(30, 2, 0, "vmcnt(4) lgkmcnt(0)", false);
    TILE(31, 3, 0, "vmcnt(0) lgkmcnt(0)", false);

    // epilogue: tanh + dot-v + per-row partial score over this block's 256 cols
    float cpv[4], vv[4];
    {
        const float* cpn = cproj + (size_t)nbatch * H_D;
        #pragma unroll
        for (int j = 0; j < 4; ++j) {
            int col = n0 + wn * 64 + j * 16 + ln;
            cpv[j] = cpn[col];
            vv[j]  = v[col];
        }
    }
    #pragma unroll
    for (int i = 0; i < 8; ++i) {
        float s0 = 0.f, s1 = 0.f, s2 = 0.f, s3 = 0.f;
        #pragma unroll
        for (int j = 0; j < 4; ++j) {
            s0 += fast_tanh(acc[i][j][0] + cpv[j]) * vv[j];
            s1 += fast_tanh(acc[i][j][1] + cpv[j]) * vv[j];
            s2 += fast_tanh(acc[i][j][2] + cpv[j]) * vv[j];
            s3 += fast_tanh(acc[i][j][3] + cpv[j]) * vv[j];
        }
        #pragma unroll
        for (int off = 1; off < 16; off <<= 1) {
            s0 += __shfl_xor(s0, off);
            s1 += __shfl_xor(s1, off);
            s2 += __shfl_xor(s2, off);
            s3 += __shfl_xor(s3, off);
        }
        if (ln == 0) {
            red[wm][wn][i * 16 + q * 4 + 0] = s0;
            red[wm][wn][i * 16 + q * 4 + 1] = s1;
            red[wm][wn][i * 16 + q * 4 + 2] = s2;
            red[wm][wn][i * 16 + q * 4 + 3] = s3;
        }
    }
    __syncthreads();
    if (t < 256) {
        const int wm2 = t >> 7, row = t & 127;
        float val = red[wm2][0][row] + red[wm2][1][row]
                  + red[wm2][2][row] + red[wm2][3][row];
        spart[(size_t)nb * NT + m0 + wm2 * 128 + row] = val;
    }
}

// ---------------- softmax over T per n, summing 4 nb-partials; 1024 threads
__global__ __launch_bounds__(1024) void softmax8_kernel(
    const float* __restrict__ spart, float* __restrict__ weights)
{
    const int n = blockIdx.x;
    const int t = threadIdx.x;   // 0..1023
    __shared__ float red[1024];
    float s0 = 0.f, s1 = 0.f;
    #pragma unroll
    for (int kb = 0; kb < 4; ++kb) {
        s0 += spart[(size_t)kb * NT + n * T_S + t];
        s1 += spart[(size_t)kb * NT + n * T_S + 1024 + t];
    }
    red[t] = fmaxf(s0, s1); __syncthreads();
    for (int s = 512; s > 0; s >>= 1) {
        if (t < s) red[t] = fmaxf(red[t], red[t + s]);
        __syncthreads();
    }
    const float mx = red[0];
    __syncthreads();
    float e0 = __expf(s0 - mx), e1 = __expf(s1 - mx);
    red[t] = e0 + e1; __syncthreads();
    for (int s = 512; s > 0; s >>= 1) {
        if (t < s) red[t] += red[t + s];
        __syncthreads();
    }
    const float inv = 1.0f / red[0];
    weights[n * T_S + t] = e0 * inv;
    weights[n * T_S + 1024 + t] = e1 * inv;
}

// ---------------- context partials: cpart[tb][n][h] = sum_{t in slice} w*gru
__global__ __launch_bounds__(256) void context3_kernel(
    const ushort* __restrict__ Ab, const float* __restrict__ weights,
    float* __restrict__ cpart)
{
    const int tb = blockIdx.x;   // 0..15, 128 t each
    const int n  = blockIdx.y;   // 0..31
    const int t  = threadIdx.x;  // h-chunk: 4 h (8 B)
    float a0 = 0.f, a1 = 0.f, a2 = 0.f, a3 = 0.f;
    const float* wp = weights + n * T_S + tb * 128;
    const ushort* gp = Ab + (size_t)(n * T_S + tb * 128) * H_D + t * 4;
    #pragma unroll 8
    for (int tt = 0; tt < 128; ++tt) {
        float w = wp[tt];
        ushort4 gv = *(const ushort4*)(gp + (size_t)tt * H_D);
        a0 = fmaf(w, bf2f(gv.x), a0);
        a1 = fmaf(w, bf2f(gv.y), a1);
        a2 = fmaf(w, bf2f(gv.z), a2);
        a3 = fmaf(w, bf2f(gv.w), a3);
    }
    *(float4*)(cpart + ((size_t)tb * N_B + n) * H_D + t * 4) =
        make_float4(a0, a1, a2, a3);
}

// ---------------- out[n][h] = sum_tb cpart[tb][n][h]
__global__ __launch_bounds__(256) void reduce_kernel(
    const float* __restrict__ cpart, float* __restrict__ out)
{
    const int idx = blockIdx.x * 256 + threadIdx.x;  // 32768
    float s = 0.f;
    #pragma unroll
    for (int tb = 0; tb < 16; ++tb)
        s += cpart[(size_t)tb * (N_B * H_D) + idx];
    out[idx] = s;
}

extern "C" void kernel_launch(void* const* d_in, const int* in_sizes, int n_in,
                              void* d_out, int out_size, void* d_ws, size_t ws_size,
                              hipStream_t stream)
{
    const float* gru  = (const float*)d_in[0];
    const float* cond = (const float*)d_in[1];
    const float* W_h  = (const float*)d_in[2];
    const float* W_c  = (const float*)d_in[3];
    const float* bias = (const float*)d_in[4];
    const float* v    = (const float*)d_in[5];
    float* out = (float*)d_out;

    char* ws = (char*)d_ws;
    const size_t szAb    = (size_t)NT * H_D * 2;        // 128 MiB
    const size_t szWt    = (size_t)H_D * H_D * 2;       // 2 MiB
    const size_t szCproj = (size_t)N_B * H_D * 4;       // 128 KiB
    const size_t szSpart = (size_t)8 * NT * 4;          // 2 MiB (4 used)

    ushort* Ab    = (ushort*)ws;
    ushort* Wt    = (ushort*)(ws + szAb);
    float* cproj  = (float*)(ws + szAb + szWt);
    float* spart  = (float*)(ws + szAb + szWt + szCproj);
    float* cpart  = spart;   // reuse: spart dead after softmax; same 2 MiB
    float* wts    = (float*)(ws + szAb + szWt + szCproj + szSpart);

    hipMemsetAsync(cproj, 0, szCproj, stream);
    convert_kernel<<<65536, 256, 0, stream>>>(gru, Ab);
    transpose_kernel<<<256, 256, 0, stream>>>(W_h, Wt);
    cproj_kernel<<<dim3(128, 4), 256, 0, stream>>>(cond, W_c, bias, cproj);
    gemm4_kernel<<<1024, 512, 0, stream>>>(Ab, Wt, cproj, v, spart);
    softmax8_kernel<<<N_B, 1024, 0, stream>>>(spart, wts);
    context3_kernel<<<dim3(16, N_B), 256, 0, stream>>>(Ab, wts, cpart);
    reduce_kernel<<<128, 256, 0, stream>>>(cpart, out);
}

// Round 5
// 571.540 us; speedup vs baseline: 1.0165x; 1.0087x over previous
//
#include <hip/hip_runtime.h>
#include <hip/hip_bf16.h>

// Problem: N=32, T=2048, H=1024, D=384
#define N_B 32
#define T_S 2048
#define H_D 1024
#define D_C 384
#define NT  (N_B * T_S)   // 65536

typedef __attribute__((ext_vector_type(8))) short bf16x8;
typedef __attribute__((ext_vector_type(4))) float f32x4;

__device__ __forceinline__ ushort f2bf(float f) {
    union { float f; unsigned u; } x; x.f = f;
    unsigned u = x.u;
    unsigned r = (u + 0x7FFFu + ((u >> 16) & 1u)) >> 16;  // RNE
    return (ushort)r;
}

__device__ __forceinline__ float bf2f(ushort u) {
    union { unsigned u; float f; } x; x.u = ((unsigned)u) << 16;
    return x.f;
}

__device__ __forceinline__ float fast_tanh(float x) {
    float e = __expf(2.0f * x);
    return 1.0f - 2.0f / (e + 1.0f);
}

// ---------------- gru fp32 -> bf16, fully lane-contiguous (16B load / 8B store)
__global__ __launch_bounds__(256) void convert_kernel(
    const float* __restrict__ g, ushort* __restrict__ gb)
{
    const size_t base = ((size_t)blockIdx.x * 256 + threadIdx.x) * 4;
    float4 v = *(const float4*)(g + base);
    ushort4 o;
    o.x = f2bf(v.x); o.y = f2bf(v.y); o.z = f2bf(v.z); o.w = f2bf(v.w);
    *(ushort4*)(gb + base) = o;
}

// ---------------- W_h (H,H) fp32 -> Wt (H,H) bf16 transposed: Wt[k][h] = W_h[h][k]
__global__ __launch_bounds__(256) void transpose_kernel(
    const float* __restrict__ W, ushort* __restrict__ Wt)
{
    __shared__ ushort tile[64 * 66];
    const int bx = blockIdx.x & 15;
    const int by = blockIdx.x >> 4;
    const int t = threadIdx.x;
    #pragma unroll
    for (int i = 0; i < 16; ++i) {
        int idx = t + i * 256;
        int r = idx >> 6, c = idx & 63;
        tile[r * 66 + c] = f2bf(W[(size_t)(by * 64 + r) * H_D + bx * 64 + c]);
    }
    __syncthreads();
    #pragma unroll
    for (int i = 0; i < 16; ++i) {
        int idx = t + i * 256;
        int r = idx >> 6, c = idx & 63;
        Wt[(size_t)(bx * 64 + r) * H_D + by * 64 + c] = tile[c * 66 + r];
    }
}

// ---------------- c_proj[n,k] += sum_{d in slice} cond[n,d]*W_c[d,k] (+bias)
__global__ __launch_bounds__(256) void cproj_kernel(
    const float* __restrict__ cond, const float* __restrict__ Wc,
    const float* __restrict__ bias, float* __restrict__ cproj)
{
    const int idx = blockIdx.x * 256 + threadIdx.x;  // 32768
    const int n = idx >> 10, k = idx & 1023;
    const int d0 = blockIdx.y * 96;
    float a0 = (blockIdx.y == 0) ? bias[k] : 0.f;
    float a1 = 0.f, a2 = 0.f, a3 = 0.f;
    const float* cp = cond + n * D_C;
    for (int d = d0; d < d0 + 96; d += 4) {
        a0 = fmaf(cp[d + 0], Wc[(size_t)(d + 0) * H_D + k], a0);
        a1 = fmaf(cp[d + 1], Wc[(size_t)(d + 1) * H_D + k], a1);
        a2 = fmaf(cp[d + 2], Wc[(size_t)(d + 2) * H_D + k], a2);
        a3 = fmaf(cp[d + 3], Wc[(size_t)(d + 3) * H_D + k], a3);
    }
    atomicAdd(&cproj[idx], (a0 + a1) + (a2 + a3));
}

// ---------------- GEMM + tanh + dot-v -> per-nb partial scores
// R5 == R4 resubmit (R4 bench died with the same opaque infra error that
// R1 showed for a kernel that then passed verbatim at R2; audit found no
// hang/race path — see round notes).  REG-STAGED pipeline: R2/R3 proved
// global_load_lds fills LDS at ~16 B/cyc/CU (staging-bound at 31% MfmaUtil
// regardless of conflicts/FETCH).  Fix = HK's path: global_load_dwordx4 ->
// VGPR -> ds_write_b128.  2 LDS buffers (68 KiB), single 16-VGPR staging
// set, compiler-derived counted vmcnt before ds_write, one
// lgkmcnt(0)+s_barrier+sched_barrier(0) per K-tile.
// Swizzle f(r)=(r>>1)&3 on write and read sides (R3 measured 0 conflicts).
#define BKq 32
#define TILE_U (256 * BKq)   // 8192 ushorts = 16 KiB per buffer per tensor

__global__ __launch_bounds__(512, 2) void gemm5_kernel(
    const ushort* __restrict__ Ab, const ushort* __restrict__ Wt,
    const float* __restrict__ cproj, const float* __restrict__ v,
    float* __restrict__ spart)
{
    __shared__ __align__(16) ushort As[2][TILE_U];   // 32 KiB
    __shared__ __align__(16) ushort Bs[2][TILE_U];   // 32 KiB
    __shared__ float red[2][4][128];                 // 4 KiB

    // XCD-aware swizzle + L2-friendly mb/nb split (R3-verified: FETCH 98 MB)
    const int bid = blockIdx.x;
    const int wg  = (bid & 7) * 128 + (bid >> 3);
    const int mb  = wg >> 2;          // 256 M-blocks of 256 rows
    const int nb  = wg & 3;           // 4 N-blocks of 256 cols
    const int m0  = mb * 256;
    const int n0  = nb * 256;
    const int nbatch = mb >> 3;

    const int t = threadIdx.x;
    const int lane = t & 63;
    const int w = t >> 6;             // 0..7
    const int wm = w >> 2, wn = w & 3;
    const int ln = lane & 15, q = lane >> 4;
    const int csw = q ^ ((ln >> 1) & 3);   // read-side chunk swizzle

    // ---- staging maps (reg path): thread covers row srow, chunks c0,c0+1
    const int srow = t >> 1;          // 0..255
    const int c0   = (t & 1) * 2;     // chunk pair base (chunks of 8 elems)
    const int fsw  = (srow >> 1) & 3;
    const int wc0  = (c0 ^ fsw) * 8;
    const int wc1  = ((c0 + 1) ^ fsw) * 8;

    const ushort* aL = Ab + (size_t)(m0 + srow) * H_D + c0 * 8;
    const ushort* bL = Wt + (size_t)(n0 + srow) * H_D + c0 * 8;
    ushort* awp0 = (ushort*)As + srow * BKq + wc0;
    ushort* awp1 = (ushort*)As + srow * BKq + wc1;
    ushort* bwp0 = (ushort*)Bs + srow * BKq + wc0;
    ushort* bwp1 = (ushort*)Bs + srow * BKq + wc1;

    const ushort* aR = (const ushort*)As + (wm * 128 + ln) * BKq + csw * 8;
    const ushort* bR = (const ushort*)Bs + (wn * 64  + ln) * BKq + csw * 8;

    f32x4 acc[8][4];
    #pragma unroll
    for (int i = 0; i < 8; ++i)
        #pragma unroll
        for (int j = 0; j < 4; ++j)
            acc[i][j] = (f32x4){0.f, 0.f, 0.f, 0.f};

    bf16x8 sA0, sA1, sB0, sB1;   // single staging reg set (tile kt+1)

#define LOADS(kt) do { \
    const ushort* _a = aL + (kt) * BKq; \
    const ushort* _b = bL + (kt) * BKq; \
    sA0 = *(const bf16x8*)(_a);     sA1 = *(const bf16x8*)(_a + 8); \
    sB0 = *(const bf16x8*)(_b);     sB1 = *(const bf16x8*)(_b + 8); \
} while (0)

#define WRITES(buf) do { \
    *(bf16x8*)(awp0 + (buf) * TILE_U) = sA0; \
    *(bf16x8*)(awp1 + (buf) * TILE_U) = sA1; \
    *(bf16x8*)(bwp0 + (buf) * TILE_U) = sB0; \
    *(bf16x8*)(bwp1 + (buf) * TILE_U) = sB1; \
} while (0)

#define MF(i,j,A,B) acc[i][j] = __builtin_amdgcn_mfma_f32_16x16x32_bf16(A, B, acc[i][j], 0, 0, 0)

#define COMPUTE(RB) do { \
    const ushort* _ar = aR + (RB) * TILE_U; \
    const ushort* _br = bR + (RB) * TILE_U; \
    bf16x8 _b0 = *(const bf16x8*)(_br); \
    bf16x8 _b1 = *(const bf16x8*)(_br + 512); \
    bf16x8 _b2 = *(const bf16x8*)(_br + 1024); \
    bf16x8 _b3 = *(const bf16x8*)(_br + 1536); \
    bf16x8 _a0 = *(const bf16x8*)(_ar); \
    bf16x8 _a1 = *(const bf16x8*)(_ar + 512); \
    bf16x8 _a2 = *(const bf16x8*)(_ar + 1024); \
    bf16x8 _a3 = *(const bf16x8*)(_ar + 1536); \
    __builtin_amdgcn_s_setprio(1); \
    MF(0,0,_a0,_b0); MF(0,1,_a0,_b1); MF(0,2,_a0,_b2); MF(0,3,_a0,_b3); \
    MF(1,0,_a1,_b0); MF(1,1,_a1,_b1); MF(1,2,_a1,_b2); MF(1,3,_a1,_b3); \
    MF(2,0,_a2,_b0); MF(2,1,_a2,_b1); MF(2,2,_a2,_b2); MF(2,3,_a2,_b3); \
    MF(3,0,_a3,_b0); MF(3,1,_a3,_b1); MF(3,2,_a3,_b2); MF(3,3,_a3,_b3); \
    __builtin_amdgcn_s_setprio(0); \
    bf16x8 _a4 = *(const bf16x8*)(_ar + 2048); \
    bf16x8 _a5 = *(const bf16x8*)(_ar + 2560); \
    bf16x8 _a6 = *(const bf16x8*)(_ar + 3072); \
    bf16x8 _a7 = *(const bf16x8*)(_ar + 3584); \
    __builtin_amdgcn_s_setprio(1); \
    MF(4,0,_a4,_b0); MF(4,1,_a4,_b1); MF(4,2,_a4,_b2); MF(4,3,_a4,_b3); \
    MF(5,0,_a5,_b0); MF(5,1,_a5,_b1); MF(5,2,_a5,_b2); MF(5,3,_a5,_b3); \
    MF(6,0,_a6,_b0); MF(6,1,_a6,_b1); MF(6,2,_a6,_b2); MF(6,3,_a6,_b3); \
    MF(7,0,_a7,_b0); MF(7,1,_a7,_b1); MF(7,2,_a7,_b2); MF(7,3,_a7,_b3); \
    __builtin_amdgcn_s_setprio(0); \
} while (0)

#define FENCE do { \
    asm volatile("s_waitcnt lgkmcnt(0)" ::: "memory"); \
    __builtin_amdgcn_s_barrier(); \
    __builtin_amdgcn_sched_barrier(0); \
} while (0)

    // prologue: tile0 -> buf0 via regs; tile1 loads in flight
    LOADS(0);
    WRITES(0);
    LOADS(1);
    FENCE;

    // steady state: iter kt = {write tile kt+1 -> buf (kt+1)&1;
    //                          issue loads tile kt+2; compute buf kt&1}
    #pragma unroll 1
    for (int kt = 0; kt < 30; kt += 2) {
        WRITES(1); LOADS(kt + 2); COMPUTE(0); FENCE;
        WRITES(0); LOADS(kt + 3); COMPUTE(1); FENCE;
    }
    WRITES(1); COMPUTE(0); FENCE;    // tile 30 (writes tile 31)
    COMPUTE(1);                      // tile 31

    // epilogue: tanh + dot-v + per-row partial score over this block's 256 cols
    float cpv[4], vv[4];
    {
        const float* cpn = cproj + (size_t)nbatch * H_D;
        #pragma unroll
        for (int j = 0; j < 4; ++j) {
            int col = n0 + wn * 64 + j * 16 + ln;
            cpv[j] = cpn[col];
            vv[j]  = v[col];
        }
    }
    #pragma unroll
    for (int i = 0; i < 8; ++i) {
        float s0 = 0.f, s1 = 0.f, s2 = 0.f, s3 = 0.f;
        #pragma unroll
        for (int j = 0; j < 4; ++j) {
            s0 += fast_tanh(acc[i][j][0] + cpv[j]) * vv[j];
            s1 += fast_tanh(acc[i][j][1] + cpv[j]) * vv[j];
            s2 += fast_tanh(acc[i][j][2] + cpv[j]) * vv[j];
            s3 += fast_tanh(acc[i][j][3] + cpv[j]) * vv[j];
        }
        #pragma unroll
        for (int off = 1; off < 16; off <<= 1) {
            s0 += __shfl_xor(s0, off);
            s1 += __shfl_xor(s1, off);
            s2 += __shfl_xor(s2, off);
            s3 += __shfl_xor(s3, off);
        }
        if (ln == 0) {
            red[wm][wn][i * 16 + q * 4 + 0] = s0;
            red[wm][wn][i * 16 + q * 4 + 1] = s1;
            red[wm][wn][i * 16 + q * 4 + 2] = s2;
            red[wm][wn][i * 16 + q * 4 + 3] = s3;
        }
    }
    __syncthreads();
    if (t < 256) {
        const int wm2 = t >> 7, row = t & 127;
        float val = red[wm2][0][row] + red[wm2][1][row]
                  + red[wm2][2][row] + red[wm2][3][row];
        spart[(size_t)nb * NT + m0 + wm2 * 128 + row] = val;
    }
}

// ---------------- softmax over T per n, summing 4 nb-partials; 1024 threads
__global__ __launch_bounds__(1024) void softmax8_kernel(
    const float* __restrict__ spart, float* __restrict__ weights)
{
    const int n = blockIdx.x;
    const int t = threadIdx.x;   // 0..1023
    __shared__ float red[1024];
    float s0 = 0.f, s1 = 0.f;
    #pragma unroll
    for (int kb = 0; kb < 4; ++kb) {
        s0 += spart[(size_t)kb * NT + n * T_S + t];
        s1 += spart[(size_t)kb * NT + n * T_S + 1024 + t];
    }
    red[t] = fmaxf(s0, s1); __syncthreads();
    for (int s = 512; s > 0; s >>= 1) {
        if (t < s) red[t] = fmaxf(red[t], red[t + s]);
        __syncthreads();
    }
    const float mx = red[0];
    __syncthreads();
    float e0 = __expf(s0 - mx), e1 = __expf(s1 - mx);
    red[t] = e0 + e1; __syncthreads();
    for (int s = 512; s > 0; s >>= 1) {
        if (t < s) red[t] += red[t + s];
        __syncthreads();
    }
    const float inv = 1.0f / red[0];
    weights[n * T_S + t] = e0 * inv;
    weights[n * T_S + 1024 + t] = e1 * inv;
}

// ---------------- context partials: cpart[tb][n][h] = sum_{t in slice} w*gru
__global__ __launch_bounds__(256) void context3_kernel(
    const ushort* __restrict__ Ab, const float* __restrict__ weights,
    float* __restrict__ cpart)
{
    const int tb = blockIdx.x;   // 0..15, 128 t each
    const int n  = blockIdx.y;   // 0..31
    const int t  = threadIdx.x;  // h-chunk: 4 h (8 B)
    float a0 = 0.f, a1 = 0.f, a2 = 0.f, a3 = 0.f;
    const float* wp = weights + n * T_S + tb * 128;
    const ushort* gp = Ab + (size_t)(n * T_S + tb * 128) * H_D + t * 4;
    #pragma unroll 8
    for (int tt = 0; tt < 128; ++tt) {
        float w = wp[tt];
        ushort4 gv = *(const ushort4*)(gp + (size_t)tt * H_D);
        a0 = fmaf(w, bf2f(gv.x), a0);
        a1 = fmaf(w, bf2f(gv.y), a1);
        a2 = fmaf(w, bf2f(gv.z), a2);
        a3 = fmaf(w, bf2f(gv.w), a3);
    }
    *(float4*)(cpart + ((size_t)tb * N_B + n) * H_D + t * 4) =
        make_float4(a0, a1, a2, a3);
}

// ---------------- out[n][h] = sum_tb cpart[tb][n][h]
__global__ __launch_bounds__(256) void reduce_kernel(
    const float* __restrict__ cpart, float* __restrict__ out)
{
    const int idx = blockIdx.x * 256 + threadIdx.x;  // 32768
    float s = 0.f;
    #pragma unroll
    for (int tb = 0; tb < 16; ++tb)
        s += cpart[(size_t)tb * (N_B * H_D) + idx];
    out[idx] = s;
}

extern "C" void kernel_launch(void* const* d_in, const int* in_sizes, int n_in,
                              void* d_out, int out_size, void* d_ws, size_t ws_size,
                              hipStream_t stream)
{
    const float* gru  = (const float*)d_in[0];
    const float* cond = (const float*)d_in[1];
    const float* W_h  = (const float*)d_in[2];
    const float* W_c  = (const float*)d_in[3];
    const float* bias = (const float*)d_in[4];
    const float* v    = (const float*)d_in[5];
    float* out = (float*)d_out;

    char* ws = (char*)d_ws;
    const size_t szAb    = (size_t)NT * H_D * 2;        // 128 MiB
    const size_t szWt    = (size_t)H_D * H_D * 2;       // 2 MiB
    const size_t szCproj = (size_t)N_B * H_D * 4;       // 128 KiB
    const size_t szSpart = (size_t)8 * NT * 4;          // 2 MiB (4 used)

    ushort* Ab    = (ushort*)ws;
    ushort* Wt    = (ushort*)(ws + szAb);
    float* cproj  = (float*)(ws + szAb + szWt);
    float* spart  = (float*)(ws + szAb + szWt + szCproj);
    float* cpart  = spart;   // reuse: spart dead after softmax; same 2 MiB
    float* wts    = (float*)(ws + szAb + szWt + szCproj + szSpart);

    hipMemsetAsync(cproj, 0, szCproj, stream);
    convert_kernel<<<65536, 256, 0, stream>>>(gru, Ab);
    transpose_kernel<<<256, 256, 0, stream>>>(W_h, Wt);
    cproj_kernel<<<dim3(128, 4), 256, 0, stream>>>(cond, W_c, bias, cproj);
    gemm5_kernel<<<1024, 512, 0, stream>>>(Ab, Wt, cproj, v, spart);
    softmax8_kernel<<<N_B, 1024, 0, stream>>>(spart, wts);
    context3_kernel<<<dim3(16, N_B), 256, 0, stream>>>(Ab, wts, cpart);
    reduce_kernel<<<128, 256, 0, stream>>>(cpart, out);
}